// Round 10
// baseline (336.758 us; speedup 1.0000x reference)
//
#include <hip/hip_runtime.h>
#include <hip/hip_bf16.h>

typedef __attribute__((ext_vector_type(8))) short bf16x8;
typedef __attribute__((ext_vector_type(4))) float f32x4;

#define DH 128
#define DOUT 64

static __device__ __forceinline__ unsigned short f2bf(float f) {
    __hip_bfloat16 h = __float2bfloat16(f);
    return *(unsigned short*)&h;
}
static __device__ __forceinline__ void acc2(float& a0, float& a1, unsigned int u) {
    a0 += __uint_as_float(u << 16);
    a1 += __uint_as_float(u & 0xffff0000u);
}
static __device__ __forceinline__ void accq8(float* a, const uint4& u) {
    acc2(a[0], a[1], u.x);
    acc2(a[2], a[3], u.y);
    acc2(a[4], a[5], u.z);
    acc2(a[6], a[7], u.w);
}

// ---------------- prep: x->bf16, zero cnt, weights->bf16 transposed, zero rows, esrc default ----------------

struct WPrep {
    const float* src[8];
    unsigned short* dst[8];
};

__global__ void prep_kernel(const float* __restrict__ x, unsigned short* __restrict__ xb,
                            unsigned short* __restrict__ hA, unsigned short* __restrict__ hB,
                            int n4, WPrep p, int* __restrict__ cnt,
                            int* __restrict__ esrc, int Epad, int N_) {
    int id = blockIdx.x * blockDim.x + threadIdx.x;
    if (id < n4) {
        float4 v = ((const float4*)x)[id];
        ushort4 b;
        b.x = f2bf(v.x); b.y = f2bf(v.y); b.z = f2bf(v.z); b.w = f2bf(v.w);
        ((ushort4*)xb)[id] = b;
        return;
    }
    id -= n4;
    if (id < N_) { cnt[id] = 0; return; }
    id -= N_;
    if (id < 7 * 16384 + 8192) {
        int m, off;
        if (id < 7 * 16384) { m = id >> 14; off = id & 16383; }
        else { m = 7; off = id - 7 * 16384; }
        int shift = (m == 7) ? 6 : 7;
        int nc = 1 << shift;
        int k = off >> shift;
        int n = off & (nc - 1);
        p.dst[m][n * 128 + k] = f2bf(p.src[m][off]);
        return;
    }
    id -= 7 * 16384 + 8192;
    if (id < 3 * 128) {
        int j = id & 127, w = id >> 7;
        if (w == 0) xb[(size_t)N_ * 128 + j] = 0;
        else if (w == 1) hA[(size_t)N_ * 128 + j] = 0;
        else hB[(size_t)N_ * 128 + j] = 0;
        return;
    }
    id -= 384;
    if (id < Epad) esrc[id] = N_ << 8;  // dummy edge -> byte offset of zero row
}

// ---------------- CSR build (degrees padded to multiples of 8; esrc holds byte offsets) ----------------

__global__ void hist_kernel(const int* __restrict__ dst, int* __restrict__ cnt,
                            int* __restrict__ rank, int E, int n) {
    int e = blockIdx.x * blockDim.x + threadIdx.x;
    if (e < E) {
        int d = dst[e];
        if ((unsigned)d < (unsigned)n) rank[e] = atomicAdd(&cnt[d], 1);
    }
}

__global__ void scan1_kernel(const int* __restrict__ cnt, int* __restrict__ rp_part,
                             int* __restrict__ bsum, int n) {
    __shared__ int s[256];
    int tid = threadIdx.x;
    int i = blockIdx.x * 256 + tid;
    int v = (i < n) ? ((cnt[i] + 7) & ~7) : 0;
    s[tid] = v;
    __syncthreads();
    for (int off = 1; off < 256; off <<= 1) {
        int t = (tid >= off) ? s[tid - off] : 0;
        __syncthreads();
        s[tid] += t;
        __syncthreads();
    }
    if (i <= n) rp_part[i] = s[tid] - v;
    if (tid == 255) bsum[blockIdx.x] = s[255];
}

__global__ void scan2_kernel(int* __restrict__ bsum, int nb) {
    __shared__ int s[256];
    int tid = threadIdx.x;
    int v = (tid < nb) ? bsum[tid] : 0;
    s[tid] = v;
    __syncthreads();
    for (int off = 1; off < 256; off <<= 1) {
        int t = (tid >= off) ? s[tid - off] : 0;
        __syncthreads();
        s[tid] += t;
        __syncthreads();
    }
    if (tid < nb) bsum[tid] = s[tid] - v;
}

__global__ void scan3_fill_kernel(const int* __restrict__ rp_part, const int* __restrict__ bsum,
                                  int* __restrict__ row_ptr,
                                  const int* __restrict__ src, const int* __restrict__ dst,
                                  const int* __restrict__ rank, int* __restrict__ esrc,
                                  int n, int E) {
    int gid = blockIdx.x * blockDim.x + threadIdx.x;
    if (gid <= n) row_ptr[gid] = rp_part[gid] + bsum[gid >> 8];
    if (gid < E) {
        int d = dst[gid];
        if ((unsigned)d < (unsigned)n)
            esrc[rp_part[d] + bsum[d >> 8] + rank[gid]] = src[gid] << 8;  // byte offset
    }
}

// ---------------- fused layer: agg -> GEMM1(relu) -> GEMM2 [-> GEMM3(relu) -> GEMM4] ----------------
// 16-row M tile, 256 threads (4 waves). Gather: LDS-staged edge indices; each
// global_load_dwordx4 covers 4 DIFFERENT edge rows (quad = lane>>4 picks the edge via
// per-lane ds_read of the index; c = lane&15 picks the 16B chunk) -> 1KB per vmcnt
// slot, 4x fewer load instructions. Depth-2 pipeline => ~4KB/wave in flight.
// Quad partials reduced via shfl_xor(16/32); self row added after reduction.

template <bool HEAD>
__launch_bounds__(256, 6)
__global__ void layer_kernel(const unsigned short* __restrict__ h,
                             const int* __restrict__ rp,
                             const int* __restrict__ esrc,
                             const unsigned short* __restrict__ W1t,
                             const float* __restrict__ b1,
                             const unsigned short* __restrict__ W2t,
                             const float* __restrict__ b2,
                             const unsigned short* __restrict__ W3t,
                             const float* __restrict__ b3,
                             const unsigned short* __restrict__ W4t,
                             const float* __restrict__ b4,
                             void* __restrict__ outp, int M) {
    constexpr int LDA = 128 + 8;
    constexpr int CAP = 2048;
    __shared__ __align__(16) unsigned short As[16][LDA];
    __shared__ __align__(16) unsigned short Zs[16][LDA];
    __shared__ __align__(16) int sIdx[CAP];

    int tid = threadIdx.x;
    int wave = __builtin_amdgcn_readfirstlane(tid >> 6);
    int lane = tid & 63;
    int quad = lane >> 4;      // which edge within a group of 4
    int c = lane & 15;         // 16B chunk of a 256B row
    unsigned c16 = (unsigned)c << 4;
    int row0 = blockIdx.x * 16;
    int nd0 = row0 + wave * 4;

    const char* hc = (const char*)h;

    int wb = rp[row0];
    int C = rp[min(row0 + 16, M)] - wb;

    int b[4], e[4];
    float acc[4][8];
#pragma unroll
    for (int i = 0; i < 4; ++i) {
        int nd = nd0 + i;
        int ndc = min(nd, M);
        int nd1 = min(nd + 1, M);
        b[i] = rp[ndc] - wb;
        e[i] = rp[nd1] - wb;
#pragma unroll
        for (int j = 0; j < 8; ++j) acc[i][j] = 0.f;
    }

    for (int p0 = 0; p0 < C; p0 += CAP) {
        int cend = min(C, p0 + CAP);
        int cnt = cend - p0;
        for (int i4 = tid * 4; i4 < cnt; i4 += 1024)
            *(int4*)&sIdx[i4] = *(const int4*)&esrc[wb + p0 + i4];
        __syncthreads();
#pragma unroll
        for (int i = 0; i < 4; ++i) {
            int nb = max(b[i], p0) - p0;
            int ne = min(e[i], cend) - p0;
            if (nb < ne) {
                int j0 = sIdx[nb + quad];
                int j1 = sIdx[nb + 4 + quad];
                uint4 uA0 = *(const uint4*)(hc + (unsigned)j0 + c16);
                uint4 uA1 = *(const uint4*)(hc + (unsigned)j1 + c16);
                for (int r = nb + 8; r < ne; r += 8) {
                    int k0 = sIdx[r + quad];
                    int k1 = sIdx[r + 4 + quad];
                    uint4 uB0 = *(const uint4*)(hc + (unsigned)k0 + c16);
                    uint4 uB1 = *(const uint4*)(hc + (unsigned)k1 + c16);
                    accq8(acc[i], uA0);
                    accq8(acc[i], uA1);
                    uA0 = uB0;
                    uA1 = uB1;
                }
                accq8(acc[i], uA0);
                accq8(acc[i], uA1);
            }
        }
        __syncthreads();
    }

    // reduce over quads, add self, pack to LDS
#pragma unroll
    for (int i = 0; i < 4; ++i) {
        int ndc = min(nd0 + i, M);
#pragma unroll
        for (int j = 0; j < 8; ++j) {
            float v = acc[i][j];
            v += __shfl_xor(v, 16, 64);
            v += __shfl_xor(v, 32, 64);
            acc[i][j] = v;
        }
        uint4 s = *(const uint4*)(hc + ((size_t)(unsigned)ndc << 8) + c16);
        accq8(acc[i], s);
        if (quad == 0) {
            uint4 ov;
            ov.x = (unsigned)f2bf(acc[i][0]) | ((unsigned)f2bf(acc[i][1]) << 16);
            ov.y = (unsigned)f2bf(acc[i][2]) | ((unsigned)f2bf(acc[i][3]) << 16);
            ov.z = (unsigned)f2bf(acc[i][4]) | ((unsigned)f2bf(acc[i][5]) << 16);
            ov.w = (unsigned)f2bf(acc[i][6]) | ((unsigned)f2bf(acc[i][7]) << 16);
            *(uint4*)(&As[wave * 4 + i][c * 8]) = ov;
        }
    }
    __syncthreads();

    int l16 = lane & 15;

    // ---- GEMM1: Zs = relu(As @ W1 + b1) ----
    bf16x8 af[4];
#pragma unroll
    for (int kt = 0; kt < 4; ++kt)
        af[kt] = *(const bf16x8*)(&As[l16][kt * 32 + quad * 8]);
#pragma unroll
    for (int p = 0; p < 2; ++p) {
        int ncol = (wave * 2 + p) * 16 + l16;
        const unsigned short* wp = W1t + ncol * 128 + quad * 8;
        f32x4 a = {0.f, 0.f, 0.f, 0.f};
#pragma unroll
        for (int kt = 0; kt < 4; ++kt)
            a = __builtin_amdgcn_mfma_f32_16x16x32_bf16(
                af[kt], *(const bf16x8*)(wp + kt * 32), a, 0, 0, 0);
        float bs = b1[ncol];
#pragma unroll
        for (int r = 0; r < 4; ++r) {
            float v = a[r] + bs;
            if (v < 0.f) v = 0.f;
            Zs[quad * 4 + r][ncol] = f2bf(v);
        }
    }
    __syncthreads();

    // ---- GEMM2: relu(Zs @ W2 + b2) -> global bf16 (conv) or As (head) ----
    bf16x8 zf[4];
#pragma unroll
    for (int kt = 0; kt < 4; ++kt)
        zf[kt] = *(const bf16x8*)(&Zs[l16][kt * 32 + quad * 8]);
#pragma unroll
    for (int p = 0; p < 2; ++p) {
        int ncol = (wave * 2 + p) * 16 + l16;
        const unsigned short* wp = W2t + ncol * 128 + quad * 8;
        f32x4 a = {0.f, 0.f, 0.f, 0.f};
#pragma unroll
        for (int kt = 0; kt < 4; ++kt)
            a = __builtin_amdgcn_mfma_f32_16x16x32_bf16(
                zf[kt], *(const bf16x8*)(wp + kt * 32), a, 0, 0, 0);
        float bs = b2[ncol];
#pragma unroll
        for (int r = 0; r < 4; ++r) {
            float v = a[r] + bs;
            if (v < 0.f) v = 0.f;
            if (HEAD) {
                As[quad * 4 + r][ncol] = f2bf(v);
            } else {
                int grow = row0 + quad * 4 + r;
                if (grow < M)
                    ((unsigned short*)outp)[(size_t)grow * 128 + ncol] = f2bf(v);
            }
        }
    }

    if (HEAD) {
        __syncthreads();
        // ---- GEMM3: Zs = relu(As @ W3 + b3) ----
        bf16x8 hf[4];
#pragma unroll
        for (int kt = 0; kt < 4; ++kt)
            hf[kt] = *(const bf16x8*)(&As[l16][kt * 32 + quad * 8]);
#pragma unroll
        for (int p = 0; p < 2; ++p) {
            int ncol = (wave * 2 + p) * 16 + l16;
            const unsigned short* wp = W3t + ncol * 128 + quad * 8;
            f32x4 a = {0.f, 0.f, 0.f, 0.f};
#pragma unroll
            for (int kt = 0; kt < 4; ++kt)
                a = __builtin_amdgcn_mfma_f32_16x16x32_bf16(
                    hf[kt], *(const bf16x8*)(wp + kt * 32), a, 0, 0, 0);
            float bs = b3[ncol];
#pragma unroll
            for (int r = 0; r < 4; ++r) {
                float v = a[r] + bs;
                if (v < 0.f) v = 0.f;
                Zs[quad * 4 + r][ncol] = f2bf(v);
            }
        }
        __syncthreads();
        // ---- GEMM4: d_out = Zs @ W4 + b4 (fp32, 64 cols) ----
        bf16x8 gf[4];
#pragma unroll
        for (int kt = 0; kt < 4; ++kt)
            gf[kt] = *(const bf16x8*)(&Zs[l16][kt * 32 + quad * 8]);
        {
            int ncol = wave * 16 + l16;
            const unsigned short* wp = W4t + ncol * 128 + quad * 8;
            f32x4 a = {0.f, 0.f, 0.f, 0.f};
#pragma unroll
            for (int kt = 0; kt < 4; ++kt)
                a = __builtin_amdgcn_mfma_f32_16x16x32_bf16(
                    gf[kt], *(const bf16x8*)(wp + kt * 32), a, 0, 0, 0);
            float bs = b4[ncol];
#pragma unroll
            for (int r = 0; r < 4; ++r) {
                int grow = row0 + quad * 4 + r;
                if (grow < M)
                    ((float*)outp)[(size_t)grow * 64 + ncol] = a[r] + bs;
            }
        }
    }
}

// ---------------- launch ----------------

extern "C" void kernel_launch(void* const* d_in, const int* in_sizes, int n_in,
                              void* d_out, int out_size, void* d_ws, size_t ws_size,
                              hipStream_t stream) {
    const float* x = (const float*)d_in[0];
    const int* ei = (const int*)d_in[1];
    int N = in_sizes[0] / DH;
    int E = in_sizes[1] / 2;
    const int* src = ei;
    const int* dstv = ei + E;
    int Epad = E + 7 * N + 1024;  // worst-case padded edge count + slack

    char* ws = (char*)d_ws;
    size_t off = 0;
    auto alloc = [&](size_t bytes) -> void* {
        void* p = ws + off;
        off += (bytes + 255) & ~(size_t)255;
        return p;
    };
    // feature buffers have N+1 rows; row N is the zero row
    unsigned short* xb = (unsigned short*)alloc((size_t)(N + 1) * DH * 2);
    unsigned short* hA = (unsigned short*)alloc((size_t)(N + 1) * DH * 2);
    unsigned short* hB = (unsigned short*)alloc((size_t)(N + 1) * DH * 2);
    unsigned short* wt[8];
    for (int m = 0; m < 8; ++m) wt[m] = (unsigned short*)alloc(16384 * 2);
    int* cnt     = (int*)alloc((size_t)N * 4);
    int* rp_part = (int*)alloc((size_t)(N + 1) * 4);
    int* row_ptr = (int*)alloc((size_t)(N + 1) * 4);
    int* rank    = (int*)alloc((size_t)E * 4);
    int* bsum    = (int*)alloc(256 * 4);
    int* esrc    = (int*)alloc((size_t)Epad * 4);

    WPrep wp;
    wp.src[0] = (const float*)d_in[2];
    wp.src[1] = (const float*)d_in[4];
    wp.src[2] = (const float*)d_in[6];
    wp.src[3] = (const float*)d_in[8];
    wp.src[4] = (const float*)d_in[10];
    wp.src[5] = (const float*)d_in[12];
    wp.src[6] = (const float*)d_in[14];
    wp.src[7] = (const float*)d_in[16];
    for (int m = 0; m < 8; ++m) wp.dst[m] = wt[m];
    int n4 = N * DH / 4;
    int prep_items = n4 + N + 7 * 16384 + 8192 + 384 + Epad;
    prep_kernel<<<(prep_items + 255) / 256, 256, 0, stream>>>(
        x, xb, hA, hB, n4, wp, cnt, esrc, Epad, N);

    int nb = (N + 1 + 255) / 256;
    int eb = (E + 255) / 256;
    hist_kernel<<<eb, 256, 0, stream>>>(dstv, cnt, rank, E, N);
    scan1_kernel<<<nb, 256, 0, stream>>>(cnt, rp_part, bsum, N);
    scan2_kernel<<<1, 256, 0, stream>>>(bsum, nb);
    scan3_fill_kernel<<<eb, 256, 0, stream>>>(rp_part, bsum, row_ptr,
                                              src, dstv, rank, esrc, N, E);

    int gb = (N + 15) / 16;

    const float* c1b1 = (const float*)d_in[3];
    const float* c1b2 = (const float*)d_in[5];
    const float* c2b1 = (const float*)d_in[7];
    const float* c2b2 = (const float*)d_in[9];
    const float* c3b1 = (const float*)d_in[11];
    const float* c3b2 = (const float*)d_in[13];
    const float* l1b  = (const float*)d_in[15];
    const float* l2b  = (const float*)d_in[17];

    layer_kernel<false><<<gb, 256, 0, stream>>>(
        xb, row_ptr, esrc, wt[0], c1b1, wt[1], c1b2,
        nullptr, nullptr, nullptr, nullptr, hA, N);
    layer_kernel<false><<<gb, 256, 0, stream>>>(
        hA, row_ptr, esrc, wt[2], c2b1, wt[3], c2b2,
        nullptr, nullptr, nullptr, nullptr, hB, N);
    layer_kernel<true><<<gb, 256, 0, stream>>>(
        hB, row_ptr, esrc, wt[4], c3b1, wt[5], c3b2,
        wt[6], l1b, wt[7], l2b, d_out, N);
}

// Round 11
// 331.223 us; speedup vs baseline: 1.0167x; 1.0167x over previous
//
#include <hip/hip_runtime.h>
#include <hip/hip_bf16.h>

typedef __attribute__((ext_vector_type(8))) short bf16x8;
typedef __attribute__((ext_vector_type(4))) float f32x4;

#define DH 128
#define DOUT 64

static __device__ __forceinline__ unsigned short f2bf(float f) {
    __hip_bfloat16 h = __float2bfloat16(f);
    return *(unsigned short*)&h;
}
static __device__ __forceinline__ void acc2(float& a0, float& a1, unsigned int u) {
    a0 += __uint_as_float(u << 16);
    a1 += __uint_as_float(u & 0xffff0000u);
}

// ---------------- prep + hist fused (cnt pre-zeroed via hipMemsetAsync) ----------------
// items: [x->bf16 conv | weights->bf16 transposed | zero rows | edge histogram]

struct WPrep {
    const float* src[8];
    unsigned short* dst[8];
};

__global__ void prep_hist_kernel(const float* __restrict__ x, unsigned short* __restrict__ xb,
                                 unsigned short* __restrict__ hA, unsigned short* __restrict__ hB,
                                 int n4, WPrep p,
                                 const int* __restrict__ dstv, int* __restrict__ cnt,
                                 int* __restrict__ rank, int E, int N_) {
    int id = blockIdx.x * blockDim.x + threadIdx.x;
    if (id < n4) {
        float4 v = ((const float4*)x)[id];
        ushort4 b;
        b.x = f2bf(v.x); b.y = f2bf(v.y); b.z = f2bf(v.z); b.w = f2bf(v.w);
        ((ushort4*)xb)[id] = b;
        return;
    }
    id -= n4;
    if (id < 7 * 16384 + 8192) {
        int m, off;
        if (id < 7 * 16384) { m = id >> 14; off = id & 16383; }
        else { m = 7; off = id - 7 * 16384; }
        int shift = (m == 7) ? 6 : 7;
        int nc = 1 << shift;
        int k = off >> shift;
        int n = off & (nc - 1);
        p.dst[m][n * 128 + k] = f2bf(p.src[m][off]);
        return;
    }
    id -= 7 * 16384 + 8192;
    if (id < 3 * 128) {
        int j = id & 127, w = id >> 7;
        if (w == 0) xb[(size_t)N_ * 128 + j] = 0;
        else if (w == 1) hA[(size_t)N_ * 128 + j] = 0;
        else hB[(size_t)N_ * 128 + j] = 0;
        return;
    }
    id -= 384;
    if (id < E) {
        int d = dstv[id];
        if ((unsigned)d < (unsigned)N_) rank[id] = atomicAdd(&cnt[d], 1);
    }
}

// ---------------- CSR build (exact degrees, no padding; esrc holds byte offsets) ----------------

__global__ void scan1_kernel(const int* __restrict__ cnt, int* __restrict__ rp_part,
                             int* __restrict__ bsum, int n) {
    __shared__ int s[256];
    int tid = threadIdx.x;
    int i = blockIdx.x * 256 + tid;
    int v = (i < n) ? cnt[i] : 0;
    s[tid] = v;
    __syncthreads();
    for (int off = 1; off < 256; off <<= 1) {
        int t = (tid >= off) ? s[tid - off] : 0;
        __syncthreads();
        s[tid] += t;
        __syncthreads();
    }
    if (i <= n) rp_part[i] = s[tid] - v;
    if (tid == 255) bsum[blockIdx.x] = s[255];
}

// row_ptr finalize + edge fill; each block re-derives the bsum prefix in LDS (nb <= 256)
__global__ void scan3_fill_kernel(const int* __restrict__ rp_part, const int* __restrict__ bsum,
                                  int* __restrict__ row_ptr,
                                  const int* __restrict__ src, const int* __restrict__ dst,
                                  const int* __restrict__ rank, int* __restrict__ esrc,
                                  int n, int E, int nb) {
    __shared__ int sb[256];
    int tid = threadIdx.x;
    {
        int v = (tid < nb) ? bsum[tid] : 0;
        sb[tid] = v;
        __syncthreads();
        for (int off = 1; off < 256; off <<= 1) {
            int t = (tid >= off) ? sb[tid - off] : 0;
            __syncthreads();
            sb[tid] += t;
            __syncthreads();
        }
        int incl = sb[tid];
        __syncthreads();
        sb[tid] = incl - v;  // exclusive prefix
        __syncthreads();
    }
    int gid = blockIdx.x * 256 + tid;
    if (gid <= n) row_ptr[gid] = rp_part[gid] + sb[gid >> 8];
    if (gid < E) {
        int d = dst[gid];
        if ((unsigned)d < (unsigned)n)
            esrc[rp_part[d] + sb[d >> 8] + rank[gid]] = src[gid] << 8;  // byte offset
    }
}

// ---------------- fused layer: agg -> GEMM1(relu) -> GEMM2 [-> GEMM3(relu) -> GEMM4] ----------------
// 16-row M tile, 256 threads (4 waves). Gather (r5-proven form): per node, exact-bounds
// 8-deep batches of whole-row loads (64 lanes x 4B = 256B per instruction), 2/1 remainders.
// No padding -> no wasted gather bytes. esrc = prescaled byte offsets.

template <bool HEAD>
__launch_bounds__(256, 8)
__global__ void layer_kernel(const unsigned short* __restrict__ h,
                             const int* __restrict__ rp,
                             const int* __restrict__ esrc,
                             const unsigned short* __restrict__ W1t,
                             const float* __restrict__ b1,
                             const unsigned short* __restrict__ W2t,
                             const float* __restrict__ b2,
                             const unsigned short* __restrict__ W3t,
                             const float* __restrict__ b3,
                             const unsigned short* __restrict__ W4t,
                             const float* __restrict__ b4,
                             void* __restrict__ outp, int M) {
    constexpr int LDA = 128 + 8;
    __shared__ __align__(16) unsigned short As[16][LDA];
    __shared__ __align__(16) unsigned short Zs[16][LDA];

    int tid = threadIdx.x;
    int wave = __builtin_amdgcn_readfirstlane(tid >> 6);
    int lane = tid & 63;
    int row0 = blockIdx.x * 16;
    int nd0 = row0 + wave * 4;

    const char* hc = (const char*)h;
    unsigned voff = (unsigned)lane << 2;

    // ---- gather: 4 nodes sequential, exact-bounds 8-deep batches ----
#pragma unroll
    for (int i = 0; i < 4; ++i) {
        int nd = min(nd0 + i, M - 1);
        int rb = rp[nd], re = rp[nd + 1];
        unsigned su = *(const unsigned*)(hc + ((size_t)(unsigned)nd << 8) + voff);
        float a0 = 0.f, a1 = 0.f;
        int j = rb;
        for (; j + 8 <= re; j += 8) {
            int o0 = esrc[j + 0];
            int o1 = esrc[j + 1];
            int o2 = esrc[j + 2];
            int o3 = esrc[j + 3];
            int o4 = esrc[j + 4];
            int o5 = esrc[j + 5];
            int o6 = esrc[j + 6];
            int o7 = esrc[j + 7];
            unsigned u0 = *(const unsigned*)(hc + (unsigned)o0 + voff);
            unsigned u1 = *(const unsigned*)(hc + (unsigned)o1 + voff);
            unsigned u2 = *(const unsigned*)(hc + (unsigned)o2 + voff);
            unsigned u3 = *(const unsigned*)(hc + (unsigned)o3 + voff);
            unsigned u4 = *(const unsigned*)(hc + (unsigned)o4 + voff);
            unsigned u5 = *(const unsigned*)(hc + (unsigned)o5 + voff);
            unsigned u6 = *(const unsigned*)(hc + (unsigned)o6 + voff);
            unsigned u7 = *(const unsigned*)(hc + (unsigned)o7 + voff);
            acc2(a0, a1, u0);
            acc2(a0, a1, u1);
            acc2(a0, a1, u2);
            acc2(a0, a1, u3);
            acc2(a0, a1, u4);
            acc2(a0, a1, u5);
            acc2(a0, a1, u6);
            acc2(a0, a1, u7);
        }
        for (; j + 2 <= re; j += 2) {
            int o0 = esrc[j], o1 = esrc[j + 1];
            unsigned u0 = *(const unsigned*)(hc + (unsigned)o0 + voff);
            unsigned u1 = *(const unsigned*)(hc + (unsigned)o1 + voff);
            acc2(a0, a1, u0);
            acc2(a0, a1, u1);
        }
        for (; j < re; ++j) {
            int o0 = esrc[j];
            unsigned u0 = *(const unsigned*)(hc + (unsigned)o0 + voff);
            acc2(a0, a1, u0);
        }
        acc2(a0, a1, su);  // self
        unsigned pv = (unsigned)f2bf(a0) | ((unsigned)f2bf(a1) << 16);
        *(unsigned*)&As[wave * 4 + i][lane * 2] = pv;
    }
    __syncthreads();

    int quad = lane >> 4;
    int l16 = lane & 15;

    // ---- GEMM1: Zs = relu(As @ W1 + b1) ----
    bf16x8 af[4];
#pragma unroll
    for (int kt = 0; kt < 4; ++kt)
        af[kt] = *(const bf16x8*)(&As[l16][kt * 32 + quad * 8]);
#pragma unroll
    for (int p = 0; p < 2; ++p) {
        int ncol = (wave * 2 + p) * 16 + l16;
        const unsigned short* wp = W1t + ncol * 128 + quad * 8;
        f32x4 a = {0.f, 0.f, 0.f, 0.f};
#pragma unroll
        for (int kt = 0; kt < 4; ++kt)
            a = __builtin_amdgcn_mfma_f32_16x16x32_bf16(
                af[kt], *(const bf16x8*)(wp + kt * 32), a, 0, 0, 0);
        float bs = b1[ncol];
#pragma unroll
        for (int r = 0; r < 4; ++r) {
            float v = a[r] + bs;
            if (v < 0.f) v = 0.f;
            Zs[quad * 4 + r][ncol] = f2bf(v);
        }
    }
    __syncthreads();

    // ---- GEMM2: relu(Zs @ W2 + b2) -> global bf16 (conv) or As (head) ----
    bf16x8 zf[4];
#pragma unroll
    for (int kt = 0; kt < 4; ++kt)
        zf[kt] = *(const bf16x8*)(&Zs[l16][kt * 32 + quad * 8]);
#pragma unroll
    for (int p = 0; p < 2; ++p) {
        int ncol = (wave * 2 + p) * 16 + l16;
        const unsigned short* wp = W2t + ncol * 128 + quad * 8;
        f32x4 a = {0.f, 0.f, 0.f, 0.f};
#pragma unroll
        for (int kt = 0; kt < 4; ++kt)
            a = __builtin_amdgcn_mfma_f32_16x16x32_bf16(
                zf[kt], *(const bf16x8*)(wp + kt * 32), a, 0, 0, 0);
        float bs = b2[ncol];
#pragma unroll
        for (int r = 0; r < 4; ++r) {
            float v = a[r] + bs;
            if (v < 0.f) v = 0.f;
            if (HEAD) {
                As[quad * 4 + r][ncol] = f2bf(v);
            } else {
                int grow = row0 + quad * 4 + r;
                if (grow < M)
                    ((unsigned short*)outp)[(size_t)grow * 128 + ncol] = f2bf(v);
            }
        }
    }

    if (HEAD) {
        __syncthreads();
        // ---- GEMM3: Zs = relu(As @ W3 + b3) ----
        bf16x8 hf[4];
#pragma unroll
        for (int kt = 0; kt < 4; ++kt)
            hf[kt] = *(const bf16x8*)(&As[l16][kt * 32 + quad * 8]);
#pragma unroll
        for (int p = 0; p < 2; ++p) {
            int ncol = (wave * 2 + p) * 16 + l16;
            const unsigned short* wp = W3t + ncol * 128 + quad * 8;
            f32x4 a = {0.f, 0.f, 0.f, 0.f};
#pragma unroll
            for (int kt = 0; kt < 4; ++kt)
                a = __builtin_amdgcn_mfma_f32_16x16x32_bf16(
                    hf[kt], *(const bf16x8*)(wp + kt * 32), a, 0, 0, 0);
            float bs = b3[ncol];
#pragma unroll
            for (int r = 0; r < 4; ++r) {
                float v = a[r] + bs;
                if (v < 0.f) v = 0.f;
                Zs[quad * 4 + r][ncol] = f2bf(v);
            }
        }
        __syncthreads();
        // ---- GEMM4: d_out = Zs @ W4 + b4 (fp32, 64 cols) ----
        bf16x8 gf[4];
#pragma unroll
        for (int kt = 0; kt < 4; ++kt)
            gf[kt] = *(const bf16x8*)(&Zs[l16][kt * 32 + quad * 8]);
        {
            int ncol = wave * 16 + l16;
            const unsigned short* wp = W4t + ncol * 128 + quad * 8;
            f32x4 a = {0.f, 0.f, 0.f, 0.f};
#pragma unroll
            for (int kt = 0; kt < 4; ++kt)
                a = __builtin_amdgcn_mfma_f32_16x16x32_bf16(
                    gf[kt], *(const bf16x8*)(wp + kt * 32), a, 0, 0, 0);
            float bs = b4[ncol];
#pragma unroll
            for (int r = 0; r < 4; ++r) {
                int grow = row0 + quad * 4 + r;
                if (grow < M)
                    ((float*)outp)[(size_t)grow * 64 + ncol] = a[r] + bs;
            }
        }
    }
}

// ---------------- launch ----------------

extern "C" void kernel_launch(void* const* d_in, const int* in_sizes, int n_in,
                              void* d_out, int out_size, void* d_ws, size_t ws_size,
                              hipStream_t stream) {
    const float* x = (const float*)d_in[0];
    const int* ei = (const int*)d_in[1];
    int N = in_sizes[0] / DH;
    int E = in_sizes[1] / 2;
    const int* src = ei;
    const int* dstv = ei + E;

    char* ws = (char*)d_ws;
    size_t off = 0;
    auto alloc = [&](size_t bytes) -> void* {
        void* p = ws + off;
        off += (bytes + 255) & ~(size_t)255;
        return p;
    };
    // feature buffers have N+1 rows; row N is the zero row (kept for safety)
    unsigned short* xb = (unsigned short*)alloc((size_t)(N + 1) * DH * 2);
    unsigned short* hA = (unsigned short*)alloc((size_t)(N + 1) * DH * 2);
    unsigned short* hB = (unsigned short*)alloc((size_t)(N + 1) * DH * 2);
    unsigned short* wt[8];
    for (int m = 0; m < 8; ++m) wt[m] = (unsigned short*)alloc(16384 * 2);
    int* cnt     = (int*)alloc((size_t)N * 4);
    int* rp_part = (int*)alloc((size_t)(N + 1) * 4);
    int* row_ptr = (int*)alloc((size_t)(N + 1) * 4);
    int* rank    = (int*)alloc((size_t)E * 4);
    int* bsum    = (int*)alloc(256 * 4);
    int* esrc    = (int*)alloc((size_t)E * 4);

    WPrep wp;
    wp.src[0] = (const float*)d_in[2];
    wp.src[1] = (const float*)d_in[4];
    wp.src[2] = (const float*)d_in[6];
    wp.src[3] = (const float*)d_in[8];
    wp.src[4] = (const float*)d_in[10];
    wp.src[5] = (const float*)d_in[12];
    wp.src[6] = (const float*)d_in[14];
    wp.src[7] = (const float*)d_in[16];
    for (int m = 0; m < 8; ++m) wp.dst[m] = wt[m];

    hipMemsetAsync(cnt, 0, (size_t)N * 4, stream);

    int n4 = N * DH / 4;
    int prep_items = n4 + 7 * 16384 + 8192 + 384 + E;
    prep_hist_kernel<<<(prep_items + 255) / 256, 256, 0, stream>>>(
        x, xb, hA, hB, n4, wp, dstv, cnt, rank, E, N);

    int nb = (N + 255) / 256;           // blocks over nodes (for bsum indexing)
    int nb1 = (N + 1 + 255) / 256;      // covers gid == n
    int eb = (E + 255) / 256;
    scan1_kernel<<<nb1, 256, 0, stream>>>(cnt, rp_part, bsum, N);
    int s3blocks = eb > nb1 ? eb : nb1;
    scan3_fill_kernel<<<s3blocks, 256, 0, stream>>>(rp_part, bsum, row_ptr,
                                                    src, dstv, rank, esrc, N, E, nb);

    int gb = (N + 15) / 16;

    const float* c1b1 = (const float*)d_in[3];
    const float* c1b2 = (const float*)d_in[5];
    const float* c2b1 = (const float*)d_in[7];
    const float* c2b2 = (const float*)d_in[9];
    const float* c3b1 = (const float*)d_in[11];
    const float* c3b2 = (const float*)d_in[13];
    const float* l1b  = (const float*)d_in[15];
    const float* l2b  = (const float*)d_in[17];

    layer_kernel<false><<<gb, 256, 0, stream>>>(
        xb, row_ptr, esrc, wt[0], c1b1, wt[1], c1b2,
        nullptr, nullptr, nullptr, nullptr, hA, N);
    layer_kernel<false><<<gb, 256, 0, stream>>>(
        hA, row_ptr, esrc, wt[2], c2b1, wt[3], c2b2,
        nullptr, nullptr, nullptr, nullptr, hB, N);
    layer_kernel<true><<<gb, 256, 0, stream>>>(
        hB, row_ptr, esrc, wt[4], c3b1, wt[5], c3b2,
        wt[6], l1b, wt[7], l2b, d_out, N);
}